// Round 1
// baseline (436.140 us; speedup 1.0000x reference)
//
#include <hip/hip_runtime.h>
#include <math.h>

#define NEG_INF (-INFINITY)

// Use a true clang ext_vector so __builtin_nontemporal_store accepts it.
typedef float f4 __attribute__((ext_vector_type(4)));

static __device__ __forceinline__ f4 ld4(const float* p) {
    return *(const f4*)p;
}

// out[j] = max(X[j], O[j], Y[j], X[j+1], Y[j+1])
// (own-coset rows X=row i, Y=row i+1; other-coset row O=row i)
static __device__ __forceinline__ f4 pool_a(f4 X, f4 Y, f4 O, float Xe, float Ye) {
    f4 r;
    r.x = fmaxf(fmaxf(fmaxf(X.x, O.x), fmaxf(Y.x, X.y)), Y.y);
    r.y = fmaxf(fmaxf(fmaxf(X.y, O.y), fmaxf(Y.y, X.z)), Y.z);
    r.z = fmaxf(fmaxf(fmaxf(X.z, O.z), fmaxf(Y.z, X.w)), Y.w);
    r.w = fmaxf(fmaxf(fmaxf(X.w, O.w), fmaxf(Y.w, Xe)), Ye);
    return r;
}

// out[j] = max(X[j], Y[j], X[j+1], Y[j+1], Wv[j+1])
// (own-coset rows X=row i, Y=row i+1; other-coset row Wv=row i+1)
static __device__ __forceinline__ f4 pool_b(f4 X, f4 Y, f4 Wv, float Xe, float Ye, float We) {
    f4 r;
    r.x = fmaxf(fmaxf(fmaxf(X.x, Y.x), fmaxf(X.y, Y.y)), Wv.y);
    r.y = fmaxf(fmaxf(fmaxf(X.y, Y.y), fmaxf(X.z, Y.z)), Wv.z);
    r.z = fmaxf(fmaxf(fmaxf(X.z, Y.z), fmaxf(X.w, Y.w)), Wv.w);
    r.w = fmaxf(fmaxf(fmaxf(X.w, Y.w), fmaxf(Xe, Ye)), We);
    return r;
}

// out0[i][j] = max(c0[i][j], c1[i][j], c0[i+1][j], c0[i][j+1], c0[i+1][j+1])
// out1[i][j] = max(c1[i][j], c1[i+1][j], c1[i][j+1], c1[i+1][j+1], c0[i+1][j+1])
// One thread computes 4 contiguous j for TWO consecutive rows of BOTH outputs:
// loads 3 rows of each coset (middle row reused in registers -> 1.5x request amp
// instead of 2x), stores 4 float4 nontemporally (don't evict input rows from L2).
__global__ __launch_bounds__(256) void quincunx_pool2_kernel(
    const float* __restrict__ c0, const float* __restrict__ c1,
    float* __restrict__ out, long N /* elems per coset */)
{
    const int H = 512, W = 512;
    const int wq = W >> 2;   // 128 j-groups per row
    const int hp = H >> 1;   // 256 row-pairs per image

    long idx = (long)blockIdx.x * blockDim.x + threadIdx.x;
    int jg = (int)(idx & (wq - 1));          // j-group (fastest: waves stay coalesced)
    int rp = (int)((idx >> 7) & (hp - 1));   // row pair
    long p  = idx >> 15;                     // image (B*C)

    int i  = rp << 1;
    int j4 = jg << 2;
    long base = p * (long)(H * W) + (long)i * W + j4;

    const f4 ninf = {NEG_INF, NEG_INF, NEG_INF, NEG_INF};

    // Rows i, i+1 always valid; row i+2 -inf-padded at the bottom edge.
    f4 a0 = ld4(c0 + base),     b0 = ld4(c1 + base);
    f4 a1 = ld4(c0 + base + W), b1 = ld4(c1 + base + W);
    f4 a2 = ninf, b2 = ninf;
    const bool hasI2 = (rp != hp - 1);       // wave-uniform (wave spans j-groups only)
    if (hasI2) {
        a2 = ld4(c0 + base + 2 * W);
        b2 = ld4(c1 + base + 2 * W);
    }

    // j+1 spill-over element at j4+4 (same cache line as neighbor lane's vector).
    const bool hasJ = (jg != wq - 1);
    float a0e = hasJ ? c0[base + 4] : NEG_INF;
    float b0e = hasJ ? c1[base + 4] : NEG_INF;
    float a1e = hasJ ? c0[base + W + 4] : NEG_INF;
    float b1e = hasJ ? c1[base + W + 4] : NEG_INF;
    float a2e = (hasJ && hasI2) ? c0[base + 2 * W + 4] : NEG_INF;
    float b2e = (hasJ && hasI2) ? c1[base + 2 * W + 4] : NEG_INF;

    f4 o0a = pool_a(a0, a1, b0, a0e, a1e);       // out0 row i
    f4 o1a = pool_b(b0, b1, a1, b0e, b1e, a1e);  // out1 row i
    f4 o0b = pool_a(a1, a2, b1, a1e, a2e);       // out0 row i+1
    f4 o1b = pool_b(b1, b2, a2, b1e, b2e, a2e);  // out1 row i+1

    // Output is write-once/never-read: nontemporal keeps L2 for input row reuse.
    __builtin_nontemporal_store(o0a, (f4*)(out + base));
    __builtin_nontemporal_store(o0b, (f4*)(out + base + W));
    __builtin_nontemporal_store(o1a, (f4*)(out + N + base));
    __builtin_nontemporal_store(o1b, (f4*)(out + N + base + W));
}

extern "C" void kernel_launch(void* const* d_in, const int* in_sizes, int n_in,
                              void* d_out, int out_size, void* d_ws, size_t ws_size,
                              hipStream_t stream) {
    const float* c0 = (const float*)d_in[0];
    const float* c1 = (const float*)d_in[1];
    float* out = (float*)d_out;

    long N = (long)in_sizes[0];              // elements per coset = 4*32*512*512
    long total_threads = N / 8;              // 4 cols x 2 rows per thread
    int threads = 256;
    int blocks = (int)((total_threads + threads - 1) / threads);

    quincunx_pool2_kernel<<<blocks, threads, 0, stream>>>(c0, c1, out, N);
}